// Round 21
// baseline (303.855 us; speedup 1.0000x reference)
//
#include <hip/hip_runtime.h>

typedef __bf16 bf16;
typedef __bf16 bf16x8 __attribute__((ext_vector_type(8)));
typedef __bf16 bf16x4v __attribute__((ext_vector_type(4)));
typedef short s16x4 __attribute__((ext_vector_type(4)));
typedef float f32x4 __attribute__((ext_vector_type(4)));
typedef unsigned int u32;
typedef unsigned long long u64;

#define NN 384
#define CC 128
#define LOG2E 1.44269504088896f

#define MFMA16(a,b,c) __builtin_amdgcn_mfma_f32_16x16x32_bf16(a,b,c,0,0,0)

// native transcendentals
#if __has_builtin(__builtin_amdgcn_exp2f)
#define FEXP2(x) __builtin_amdgcn_exp2f(x)
#else
#define FEXP2(x) exp2f(x)
#endif
#define FRCP(x)  __builtin_amdgcn_rcpf(x)

// 16x16x16 bf16 MFMA
#if __has_builtin(__builtin_amdgcn_mfma_f32_16x16x16_bf16)
typedef bf16x4v pvab_t;
static __device__ __forceinline__ f32x4 PVMFMA(pvab_t A, bf16x4v B, f32x4 C){
  return __builtin_amdgcn_mfma_f32_16x16x16_bf16(A, B, C, 0,0,0);
}
#else
typedef s16x4 pvab_t;
static __device__ __forceinline__ f32x4 PVMFMA(pvab_t A, bf16x4v B, f32x4 C){
  return __builtin_amdgcn_mfma_f32_16x16x16bf16_1k(A, __builtin_bit_cast(s16x4, B), C, 0,0,0);
}
#endif
static __device__ __forceinline__ pvab_t mk_pvab(u32 w0, u32 w1){
  return __builtin_bit_cast(pvab_t, (u64)w0 | ((u64)w1<<32));
}

static __device__ __forceinline__ u32 bpack(float a, float b){
  unsigned short x = __builtin_bit_cast(unsigned short, (bf16)a);
  unsigned short y = __builtin_bit_cast(unsigned short, (bf16)b);
  return (u32)x | ((u32)y<<16);
}

// ---------------- workspace layout (bytes) ----------------
#define WS_NB   37748736          // nb fp32 [h][q][k] (pre-scaled by log2e)
#define WS_QKVG 40108032          // qkvg B-frag pack
#define WS_OP   40239104          // o_w pack
#define WS_KB   40271872          // K A-frag32 bf16 [b][h][24x1KiB]; reused as wavg
#define WS_VB   78020608          // V B16-frags bf16 [b][h][24x1KiB] (masked rows ZEROED — required)
#define WS_NEED 115769344

__device__ __forceinline__ void async_copy16(void* lds_dst, const void* gsrc){
  __builtin_amdgcn_global_load_lds((const __attribute__((address_space(1))) u32*)gsrc,
                                   (__attribute__((address_space(3))) u32*)lds_dst, 16, 0, 0);
}

// ---------------- K0: pre-pack weights into MFMA B-fragment order ----------------
__global__ __launch_bounds__(256) void pack_kernel(
    const float* __restrict__ qw, const float* __restrict__ kw,
    const float* __restrict__ vw, const float* __restrict__ gw,
    const float* __restrict__ ow, bf16* __restrict__ qkvg, bf16* __restrict__ op)
{
  int tid = blockIdx.x*256 + threadIdx.x;
  int lane = tid & 63, frag = tid >> 6;
  if (frag < 128) {                       // ((wm*4+h)*4+t)*2+f
    int f = frag & 1, t = (frag>>1)&3, h = (frag>>3)&3, wm = frag>>5;
    const float* W = wm==0?qw: (wm==1?kw: (wm==2?vw: gw));
    float sc = (wm==0) ? 0.17677669529663687f*LOG2E : (wm==3 ? LOG2E : 1.0f);
    int d = f*16 + (lane&15);
    #pragma unroll
    for (int j=0;j<8;j++){
      int c = t*32 + (lane>>4)*8 + j;
      qkvg[tid*8 + j] = (bf16)(W[c*128 + h*32 + d]*sc);
    }
  } else if (frag < 160) {                // o_w
    int fr = frag - 128, f = fr & 7, t = fr>>3;
    int c = f*16 + (lane&15);
    #pragma unroll
    for (int j=0;j<8;j++){
      int d = (lane>>4)*8 + j;
      op[(fr*64 + lane)*8 + j] = (bf16)ow[(t*32 + d)*128 + c];
    }
  }
}

// ---------------- K1: LayerNorm (fp32) -> x bf16, + nb_bias [h][q][k] * log2e ----------------
__global__ __launch_bounds__(256) void ln_kernel(
    const float* __restrict__ pa, const float* __restrict__ lns,
    const float* __restrict__ lnb, const float* __restrict__ fw,
    bf16* __restrict__ xout, float* __restrict__ nbout)
{
  int wid = (blockIdx.x*256 + threadIdx.x) >> 6;
  int lane = threadIdx.x & 63;
  int nw = (gridDim.x*256) >> 6;
  float2 sc = *(const float2*)(lns + lane*2);
  float2 bi = *(const float2*)(lnb + lane*2);
  float4 f0 = *(const float4*)(fw + lane*8);
  float4 f1 = *(const float4*)(fw + lane*8 + 4);
  for (int row = wid; row < NN*NN; row += nw){
    float2 v = *(const float2*)(pa + row*128 + lane*2);
    float s = v.x + v.y;
    float sq = v.x*v.x + v.y*v.y;
    #pragma unroll
    for (int m=1;m<64;m<<=1){ s += __shfl_xor(s,m); sq += __shfl_xor(sq,m); }
    float mu = s*(1.f/128.f);
    float rstd = rsqrtf(sq*(1.f/128.f) - mu*mu + 1e-5f);
    float x0 = (v.x-mu)*rstd*sc.x + bi.x;
    float x1 = (v.y-mu)*rstd*sc.y + bi.y;
    unsigned short h0 = __builtin_bit_cast(unsigned short, (bf16)x0);
    unsigned short h1 = __builtin_bit_cast(unsigned short, (bf16)x1);
    *(unsigned int*)((char*)xout + row*256 + lane*4) = ((unsigned int)h1<<16)|h0;
    float4 t;
    t.x = x0*f0.x + x1*f1.x;
    t.y = x0*f0.y + x1*f1.y;
    t.z = x0*f0.z + x1*f1.z;
    t.w = x0*f0.w + x1*f1.w;
    #pragma unroll
    for (int m=1;m<64;m<<=1){
      t.x += __shfl_xor(t.x,m); t.y += __shfl_xor(t.y,m);
      t.z += __shfl_xor(t.z,m); t.w += __shfl_xor(t.w,m);
    }
    float vsel = (lane==0)?t.x : (lane==1)?t.y : (lane==2)?t.z : t.w;
    if (lane < 4) nbout[(size_t)lane*(NN*NN) + row] = vsel*LOG2E;
  }
}

// ---------------- K2: K/V projection GEMM -> fragment-packed buffers ----------------
__global__ __launch_bounds__(256) void proj_kv_kernel(
    const bf16* __restrict__ xg, const bf16* __restrict__ qkvg,
    const int* __restrict__ mask, bf16* __restrict__ kbuf, bf16* __restrict__ vbuf)
{
  __shared__ char psm[16384];
  const int w = threadIdx.x>>6, lane = threadIdx.x&63, g = (lane>>4)&3, l15 = lane&15;
  const int W = blockIdx.x*4 + w;
  const int rt = W>>1, wm = 1 + (W&1);
  const f32x4 Z = {0.f,0.f,0.f,0.f};
  f32x4 acc[8];
  #pragma unroll
  for (int f8=0;f8<8;f8++) acc[f8] = Z;
  const bf16* xrow = xg + (size_t)(rt*16 + l15)*CC;
  #pragma unroll
  for (int t=0;t<4;t++){
    bf16x8 a = *(const bf16x8*)(xrow + t*32 + g*8);
    #pragma unroll
    for (int f8=0; f8<8; f8++){
      int h = f8>>1, fh = f8&1;
      bf16x8 bb = *(const bf16x8*)(qkvg + (((wm*4+h)*4+t)*2+fh)*512 + lane*8);
      acc[f8] = MFMA16(a, bb, acc[f8]);
    }
  }
  const int bq = rt/24, tau = rt%24;
  if (wm==1){
    char* scr = psm + w*4096;
    #pragma unroll
    for (int f8=0; f8<8; f8++){
      #pragma unroll
      for (int j=0;j<4;j++){
        unsigned r = g*4+j;
        *(bf16*)(scr + ((r*256 + (f8*16+l15)*2) ^ (((r>>1)&7)<<4))) = (bf16)acc[f8][j];
      }
    }
    #pragma unroll
    for (int h=0;h<4;h++){
      bf16x8 kf = *(const bf16x8*)(scr + ((l15*256 + h*64 + g*16) ^ (((l15>>1)&7)<<4)));
      *(bf16x8*)(kbuf + (((size_t)(bq*4+h)*24 + tau)*64 + lane)*8) = kf;
    }
  } else {
    int4 mi = *(const int4*)(mask + bq*NN + tau*16 + g*4);
    float mb[4] = { mi.x?1.f:0.f, mi.y?1.f:0.f, mi.z?1.f:0.f, mi.w?1.f:0.f };
    #pragma unroll
    for (int f8=0; f8<8; f8++){
      #pragma unroll
      for (int j=0;j<4;j++) acc[f8][j] *= mb[j];
    }
    #pragma unroll
    for (int h=0;h<4;h++){
      f32x4 a0 = acc[h*2+0], a1 = acc[h*2+1];
      uint4 st4;
      st4.x = bpack(a0[0], a0[1]);
      st4.y = bpack(a0[2], a0[3]);
      st4.z = bpack(a1[0], a1[1]);
      st4.w = bpack(a1[2], a1[3]);
      *(uint4*)((char*)vbuf + ((size_t)(bq*4+h)*24 + tau)*1024 + lane*16) = st4;
    }
  }
}

// ---------------- K3: attention v21 = v20 + LDS diet (V from L2) ----------------
// Counter-driven: v20's limiter is LDS (58.9KB -> 2 blocks/CU -> 2 waves/EU;
// registers ~130 total would allow 3). Drop V staging: vv frags read from
// global/L2 per chunk (shared across the tile pair = half the loads of v15's
// single-tile variant, prefetched ahead of the S MFMAs). LDS 58.9 -> 34.3 KB
// -> 4 blocks/CU by LDS; runtime waves = min(regs ~3, attr max 4) = 3/EU.
#define L21_SCR  24576            // 4 waves x 2 KiB scratch (1 KiB per tile slot)
#define L21_MASK 32768            // fp32 0/1 [384]
#define L21_TOT  34304

__global__ __attribute__((amdgpu_flat_work_group_size(256,256), amdgpu_waves_per_eu(2,4)))
void attn_kernel21(
    const bf16* __restrict__ xg, const int* __restrict__ mask,
    const float* __restrict__ nb, const bf16* __restrict__ qkvg,
    bf16* __restrict__ kbuf, const bf16* __restrict__ vbuf,
    const float* __restrict__ gb)
{
  __shared__ char sm[L21_TOT];
  const int tid = threadIdx.x;
  const int lane = tid & 63, w = tid >> 6;
  const int g = (lane >> 4)&3, l15 = lane & 15;
  const f32x4 Z = {0.f,0.f,0.f,0.f};

  // h-major: concurrent blocks share one nb[h] plane (L2-resident)
  const u32 bid = blockIdx.x;
  const int h = bid / 384;
  const int b = bid - h*384;

  const char* kbh = (const char*)kbuf + ((size_t)b*4 + h)*24576;
  const char* vbh = (const char*)vbuf + ((size_t)b*4 + h)*24576;

  // ---- stage K (24KiB) + mask 0/1 fp32 (1.5KiB); V stays in L2 ----
  #pragma unroll
  for (int i=0;i<6;i++){
    unsigned u = (i*4 + w)*1024;
    async_copy16(sm + u, kbh + u + lane*16);
  }
  for (int k = tid; k < NN; k += 256)
    *(float*)(sm + L21_MASK + k*4) = (mask[b*NN + k] != 0) ? 1.f : 0.f;
  __syncthreads();   // vmcnt+lgkm drain; all staging visible

  const unsigned scbA = L21_SCR + w*2048;
  const unsigned scbB = scbA + 1024;
  const float* nbh = nb + (size_t)h*(NN*NN);

  for (int i=0;i<3;i++){
    const int qtA = w*6 + i*2, qtB = qtA + 1;
    const int qbA = qtA*16,    qbB = qtB*16;

    // x A-frags for both q-tiles
    bf16x8 a4A[4], a4B[4];
    #pragma unroll
    for (int t=0;t<4;t++){
      a4A[t] = *(const bf16x8*)(xg + (size_t)(b*NN + qbA + l15)*CC + t*32 + g*8);
      a4B[t] = *(const bf16x8*)(xg + (size_t)(b*NN + qbB + l15)*CC + t*32 + g*8);
    }

    // ---- Q projections (weight frags shared) ----
    f32x4 qA0=Z, qA1=Z, qB0=Z, qB1=Z;
    #pragma unroll
    for (int t=0;t<4;t++){
      bf16x8 bq0 = *(const bf16x8*)(qkvg + (((0*4+h)*4+t)*2+0)*512 + lane*8);
      bf16x8 bq1 = *(const bf16x8*)(qkvg + (((0*4+h)*4+t)*2+1)*512 + lane*8);
      qA0 = MFMA16(a4A[t], bq0, qA0);
      qA1 = MFMA16(a4A[t], bq1, qA1);
      qB0 = MFMA16(a4B[t], bq0, qB0);
      qB1 = MFMA16(a4B[t], bq1, qB1);
    }
    // bounce both Q accums -> B-frags (separate slots; independent lgkm chains)
    #pragma unroll
    for (int f=0;f<2;f++){
      f32x4 qqA = f ? qA1 : qA0, qqB = f ? qB1 : qB0;
      #pragma unroll
      for (int j=0;j<4;j++){
        unsigned r = g*4 + j, cb = (f*16 + l15)*2;
        unsigned off = (r*64 + cb) ^ (((r>>1)&7)<<4);
        *(bf16*)(sm + scbA + off) = (bf16)qqA[j];
        *(bf16*)(sm + scbB + off) = (bf16)qqB[j];
      }
    }
    unsigned aqoff = (l15*64 + g*16) ^ (((l15>>1)&7)<<4);
    bf16x8 aqA = *(const bf16x8*)(sm + scbA + aqoff);
    bf16x8 aqB = *(const bf16x8*)(sm + scbB + aqoff);

    // ---- dual fixed-max softmax (no mask add) + register PV, six 64-key chunks ----
    float sumA = 0.f, sumB = 0.f;
    f32x4 oA0=Z, oA1=Z, oB0=Z, oB1=Z;
    const float* nbqA = nbh + (size_t)(qbA + l15)*NN;
    const float* nbqB = nbh + (size_t)(qbB + l15)*NN;

    #pragma unroll
    for (int c=0;c<6;c++){
      // V prefetch for this chunk from L2 (shared by both tiles; overlaps S MFMAs)
      bf16x8 vv[4];
      #pragma unroll
      for (int nf=0;nf<4;nf++)
        vv[nf] = *(const bf16x8*)(vbh + (c*4+nf)*1024 + lane*16);

      f32x4 stA[4], stB[4];
      #pragma unroll
      for (int nf=0;nf<4;nf++){
        bf16x8 ka = *(const bf16x8*)(sm + (c*4+nf)*1024 + lane*16);   // shared (LDS)
        float4 nbvA = *(const float4*)(nbqA + c*64 + nf*16 + g*4);
        float4 nbvB = *(const float4*)(nbqB + c*64 + nf*16 + g*4);
        stA[nf] = MFMA16(ka, aqA, __builtin_bit_cast(f32x4, nbvA));
        stB[nf] = MFMA16(ka, aqB, __builtin_bit_cast(f32x4, nbvB));
      }
      #pragma unroll
      for (int nf=0;nf<4;nf++){
        float4 mkf = *(const float4*)(sm + L21_MASK + (c*64 + nf*16 + g*4)*4);  // shared 0/1
        const float* mk = &mkf.x;
        #pragma unroll
        for (int j=0;j<4;j++){
          float pvA = FEXP2(stA[nf][j] - 28.8539008178f);   // == exp(S - 20), no mask term
          float pvB = FEXP2(stB[nf][j] - 28.8539008178f);
          stA[nf][j] = pvA; sumA += pvA*mk[j];              // masked keys excluded via fmac
          stB[nf][j] = pvB; sumB += pvB*mk[j];
        }
      }
      #pragma unroll
      for (int nf=0;nf<4;nf++){
        bf16x4v vlo = {vv[nf][0],vv[nf][1],vv[nf][2],vv[nf][3]};
        bf16x4v vhi = {vv[nf][4],vv[nf][5],vv[nf][6],vv[nf][7]};
        pvab_t paA = mk_pvab(bpack(stA[nf][0], stA[nf][1]), bpack(stA[nf][2], stA[nf][3]));
        pvab_t paB = mk_pvab(bpack(stB[nf][0], stB[nf][1]), bpack(stB[nf][2], stB[nf][3]));
        oA0 = PVMFMA(paA, vlo, oA0);
        oB0 = PVMFMA(paB, vlo, oB0);
        oA1 = PVMFMA(paA, vhi, oA1);
        oB1 = PVMFMA(paB, vhi, oB1);
      }
    } // c

    // deferred cross-lane sum reduces + broadcast to C/D rows
    sumA += __shfl_xor(sumA, 16); sumA += __shfl_xor(sumA, 32);
    sumB += __shfl_xor(sumB, 16); sumB += __shfl_xor(sumB, 32);
    float rslA = FRCP(sumA), rslB = FRCP(sumB);
    float rcdA[4], rcdB[4];
    #pragma unroll
    for (int j=0;j<4;j++){
      int src = (lane & 0x30) + g*4 + j;
      rcdA[j] = __shfl(rslA, src);
      rcdB[j] = __shfl(rslB, src);
    }

    // ---- gate projections (weight frags shared) ----
    f32x4 gA0=Z, gA1=Z, gB0=Z, gB1=Z;
    #pragma unroll
    for (int t=0;t<4;t++){
      bf16x8 bg0 = *(const bf16x8*)(qkvg + (((3*4+h)*4+t)*2+0)*512 + lane*8);
      bf16x8 bg1 = *(const bf16x8*)(qkvg + (((3*4+h)*4+t)*2+1)*512 + lane*8);
      gA0 = MFMA16(a4A[t], bg0, gA0);
      gA1 = MFMA16(a4A[t], bg1, gA1);
      gB0 = MFMA16(a4B[t], bg0, gB0);
      gB1 = MFMA16(a4B[t], bg1, gB1);
    }

    // ---- wg = (O/s)*sigmoid; bounce to A-frag per slot; store both wavg ----
    #pragma unroll
    for (int f=0;f<2;f++){
      f32x4 ovA = f ? oA1 : oA0, gvA = f ? gA1 : gA0;
      f32x4 ovB = f ? oB1 : oB0, gvB = f ? gB1 : gB0;
      int d = f*16 + l15;
      float gbv = gb[h*32 + d]*LOG2E;
      #pragma unroll
      for (int j=0;j<4;j++){
        unsigned r = g*4 + j, cb2 = (unsigned)d*2;
        unsigned off = (r*64 + cb2) ^ (((r>>1)&7)<<4);
        float gtA = FRCP(1.f + FEXP2(-(gvA[j] + gbv)));
        float gtB = FRCP(1.f + FEXP2(-(gvB[j] + gbv)));
        *(bf16*)(sm + scbA + off) = (bf16)(ovA[j]*rcdA[j]*gtA);
        *(bf16*)(sm + scbB + off) = (bf16)(ovB[j]*rcdB[j]*gtB);
      }
    }
    bf16x8 awgA = *(const bf16x8*)(sm + scbA + aqoff);
    bf16x8 awgB = *(const bf16x8*)(sm + scbB + aqoff);
    *(bf16x8*)((char*)kbuf + ((size_t)b*4 + h)*24576 + qtA*1024 + lane*16) = awgA;
    *(bf16x8*)((char*)kbuf + ((size_t)b*4 + h)*24576 + qtB*1024 + lane*16) = awgB;
  } // i (q-tile pairs)
}

// ---------------- K4: out-projection GEMM: out = wavg · o_w + ob ----------------
__global__ __launch_bounds__(256) void outproj_kernel(
    const bf16* __restrict__ wavg, const bf16* __restrict__ opk,
    const float* __restrict__ ob, float* __restrict__ out)
{
  const int w = threadIdx.x>>6, lane = threadIdx.x&63;
  const int g = (lane>>4)&3, l15 = lane&15;
  const f32x4 Z = {0.f,0.f,0.f,0.f};
  const int W = blockIdx.x*4 + w;
  const int b = W/24, qt = W%24, qb = qt*16;

  bf16x8 aw[4];
  #pragma unroll
  for (int h=0;h<4;h++)
    aw[h] = *(const bf16x8*)((const char*)wavg + ((size_t)b*4 + h)*24576 + qt*1024 + lane*16);

  f32x4 outa[8];
  #pragma unroll
  for (int nf=0;nf<8;nf++) outa[nf] = Z;
  #pragma unroll
  for (int h=0;h<4;h++){
    #pragma unroll
    for (int nf=0;nf<8;nf++){
      bf16x8 bo = *(const bf16x8*)(opk + ((h*8+nf)*64 + lane)*8);
      outa[nf] = MFMA16(aw[h], bo, outa[nf]);
    }
  }
  #pragma unroll
  for (int nf=0;nf<8;nf++){
    int c = nf*16 + l15;
    float obv = ob[c];
    #pragma unroll
    for (int j=0;j<4;j++){
      int qi = qb + g*4 + j;
      out[((size_t)b*NN + qi)*CC + c] = outa[nf][j] + obv;
    }
  }
}

extern "C" void kernel_launch(void* const* d_in, const int* in_sizes, int n_in,
                              void* d_out, int out_size, void* d_ws, size_t ws_size,
                              hipStream_t stream)
{
  (void)in_sizes; (void)n_in; (void)out_size; (void)ws_size;
  const float* pa  = (const float*)d_in[0];
  const int*   msk = (const int*)d_in[1];
  const float* lns = (const float*)d_in[2];
  const float* lnb = (const float*)d_in[3];
  const float* fw  = (const float*)d_in[4];
  const float* qw  = (const float*)d_in[5];
  const float* kw  = (const float*)d_in[6];
  const float* vw  = (const float*)d_in[7];
  const float* gw  = (const float*)d_in[8];
  const float* gbv = (const float*)d_in[9];
  const float* ow  = (const float*)d_in[10];
  const float* ob  = (const float*)d_in[11];
  float* out = (float*)d_out;

  char* ws = (char*)d_ws;
  bf16*  xbuf  = (bf16*)(ws);
  float* nbbuf = (float*)(ws + WS_NB);
  bf16*  qkvg  = (bf16*)(ws + WS_QKVG);
  bf16*  opk   = (bf16*)(ws + WS_OP);
  bf16*  kbuf  = (bf16*)(ws + WS_KB);
  bf16*  vbuf  = (bf16*)(ws + WS_VB);

  pack_kernel<<<40, 256, 0, stream>>>(qw, kw, vw, gw, ow, qkvg, opk);
  ln_kernel<<<1152, 256, 0, stream>>>(pa, lns, lnb, fw, xbuf, nbbuf);
  proj_kv_kernel<<<4608, 256, 0, stream>>>(xbuf, qkvg, msk, kbuf, vbuf);
  attn_kernel21<<<1536, 256, 0, stream>>>(xbuf, msk, nbbuf, qkvg, kbuf, vbuf, gbv);
  outproj_kernel<<<2304, 256, 0, stream>>>(kbuf, opk, ob, out);
}

// Round 22
// 266.487 us; speedup vs baseline: 1.1402x; 1.1402x over previous
//
#include <hip/hip_runtime.h>

typedef __bf16 bf16;
typedef __bf16 bf16x8 __attribute__((ext_vector_type(8)));
typedef __bf16 bf16x4v __attribute__((ext_vector_type(4)));
typedef short s16x4 __attribute__((ext_vector_type(4)));
typedef float f32x4 __attribute__((ext_vector_type(4)));
typedef unsigned int u32;
typedef unsigned long long u64;

#define NN 384
#define CC 128
#define LOG2E 1.44269504088896f

#define MFMA16(a,b,c) __builtin_amdgcn_mfma_f32_16x16x32_bf16(a,b,c,0,0,0)

// native transcendentals (guarded rcp/exp sequences cost ~6-10 VALU ops each)
#if __has_builtin(__builtin_amdgcn_exp2f)
#define FEXP2(x) __builtin_amdgcn_exp2f(x)
#else
#define FEXP2(x) exp2f(x)
#endif
#define FRCP(x)  __builtin_amdgcn_rcpf(x)

// 16x16x16 bf16 MFMA
#if __has_builtin(__builtin_amdgcn_mfma_f32_16x16x16_bf16)
typedef bf16x4v pvab_t;
static __device__ __forceinline__ f32x4 PVMFMA(pvab_t A, bf16x4v B, f32x4 C){
  return __builtin_amdgcn_mfma_f32_16x16x16_bf16(A, B, C, 0,0,0);
}
#else
typedef s16x4 pvab_t;
static __device__ __forceinline__ f32x4 PVMFMA(pvab_t A, bf16x4v B, f32x4 C){
  return __builtin_amdgcn_mfma_f32_16x16x16bf16_1k(A, __builtin_bit_cast(s16x4, B), C, 0,0,0);
}
#endif
static __device__ __forceinline__ pvab_t mk_pvab(u32 w0, u32 w1){
  return __builtin_bit_cast(pvab_t, (u64)w0 | ((u64)w1<<32));
}

static __device__ __forceinline__ u32 bpack(float a, float b){
  unsigned short x = __builtin_bit_cast(unsigned short, (bf16)a);
  unsigned short y = __builtin_bit_cast(unsigned short, (bf16)b);
  return (u32)x | ((u32)y<<16);
}

// ---------------- workspace layout (bytes) ----------------
#define WS_NB   37748736          // nb fp32 [h][q][k] (pre-scaled by log2e)
#define WS_QKVG 40108032          // qkvg B-frag pack
#define WS_OP   40239104          // o_w pack
#define WS_KB   40271872          // K A-frag32 bf16 [b][h][24x1KiB]; reused as wavg
#define WS_VB   78020608          // V B16-frags bf16 [b][h][24x1KiB] (masked rows ZEROED — required)
#define WS_NEED 115769344

__device__ __forceinline__ void async_copy16(void* lds_dst, const void* gsrc){
  __builtin_amdgcn_global_load_lds((const __attribute__((address_space(1))) u32*)gsrc,
                                   (__attribute__((address_space(3))) u32*)lds_dst, 16, 0, 0);
}

// ---------------- K0: pre-pack weights into MFMA B-fragment order ----------------
// exp2-folding: q_w scaled by D^-0.5 * log2e; gating_w scaled by log2e.
__global__ __launch_bounds__(256) void pack_kernel(
    const float* __restrict__ qw, const float* __restrict__ kw,
    const float* __restrict__ vw, const float* __restrict__ gw,
    const float* __restrict__ ow, bf16* __restrict__ qkvg, bf16* __restrict__ op)
{
  int tid = blockIdx.x*256 + threadIdx.x;
  int lane = tid & 63, frag = tid >> 6;
  if (frag < 128) {                       // ((wm*4+h)*4+t)*2+f
    int f = frag & 1, t = (frag>>1)&3, h = (frag>>3)&3, wm = frag>>5;
    const float* W = wm==0?qw: (wm==1?kw: (wm==2?vw: gw));
    float sc = (wm==0) ? 0.17677669529663687f*LOG2E : (wm==3 ? LOG2E : 1.0f);
    int d = f*16 + (lane&15);
    #pragma unroll
    for (int j=0;j<8;j++){
      int c = t*32 + (lane>>4)*8 + j;
      qkvg[tid*8 + j] = (bf16)(W[c*128 + h*32 + d]*sc);
    }
  } else if (frag < 160) {                // o_w
    int fr = frag - 128, f = fr & 7, t = fr>>3;
    int c = f*16 + (lane&15);
    #pragma unroll
    for (int j=0;j<8;j++){
      int d = (lane>>4)*8 + j;
      op[(fr*64 + lane)*8 + j] = (bf16)ow[(t*32 + d)*128 + c];
    }
  }
}

// ---------------- K1: LayerNorm (fp32) -> x bf16, + nb_bias [h][q][k] * log2e ----------------
__global__ __launch_bounds__(256) void ln_kernel(
    const float* __restrict__ pa, const float* __restrict__ lns,
    const float* __restrict__ lnb, const float* __restrict__ fw,
    bf16* __restrict__ xout, float* __restrict__ nbout)
{
  int wid = (blockIdx.x*256 + threadIdx.x) >> 6;
  int lane = threadIdx.x & 63;
  int nw = (gridDim.x*256) >> 6;
  float2 sc = *(const float2*)(lns + lane*2);
  float2 bi = *(const float2*)(lnb + lane*2);
  float4 f0 = *(const float4*)(fw + lane*8);
  float4 f1 = *(const float4*)(fw + lane*8 + 4);
  for (int row = wid; row < NN*NN; row += nw){
    float2 v = *(const float2*)(pa + row*128 + lane*2);
    float s = v.x + v.y;
    float sq = v.x*v.x + v.y*v.y;
    #pragma unroll
    for (int m=1;m<64;m<<=1){ s += __shfl_xor(s,m); sq += __shfl_xor(sq,m); }
    float mu = s*(1.f/128.f);
    float rstd = rsqrtf(sq*(1.f/128.f) - mu*mu + 1e-5f);
    float x0 = (v.x-mu)*rstd*sc.x + bi.x;
    float x1 = (v.y-mu)*rstd*sc.y + bi.y;
    unsigned short h0 = __builtin_bit_cast(unsigned short, (bf16)x0);
    unsigned short h1 = __builtin_bit_cast(unsigned short, (bf16)x1);
    *(unsigned int*)((char*)xout + row*256 + lane*4) = ((unsigned int)h1<<16)|h0;
    float4 t;
    t.x = x0*f0.x + x1*f1.x;
    t.y = x0*f0.y + x1*f1.y;
    t.z = x0*f0.z + x1*f1.z;
    t.w = x0*f0.w + x1*f1.w;
    #pragma unroll
    for (int m=1;m<64;m<<=1){
      t.x += __shfl_xor(t.x,m); t.y += __shfl_xor(t.y,m);
      t.z += __shfl_xor(t.z,m); t.w += __shfl_xor(t.w,m);
    }
    float vsel = (lane==0)?t.x : (lane==1)?t.y : (lane==2)?t.z : t.w;
    if (lane < 4) nbout[(size_t)lane*(NN*NN) + row] = vsel*LOG2E;
  }
}

// ---------------- K2: K/V projection GEMM -> fragment-packed buffers ----------------
// K per (b,h,tau): A-frag32: lane holds K[key=l15][d=g*8+j] (16B/lane, 1KiB/frag)
// V per (b,h,tau): B-frag16 pair: lane holds V[key=tau*16+4g+j][d=fh*16+l15].
// Masked V ROWS ZEROED (required: mask bias dropped from S entirely).
__global__ __launch_bounds__(256) void proj_kv_kernel(
    const bf16* __restrict__ xg, const bf16* __restrict__ qkvg,
    const int* __restrict__ mask, bf16* __restrict__ kbuf, bf16* __restrict__ vbuf)
{
  __shared__ char psm[16384];
  const int w = threadIdx.x>>6, lane = threadIdx.x&63, g = (lane>>4)&3, l15 = lane&15;
  const int W = blockIdx.x*4 + w;
  const int rt = W>>1, wm = 1 + (W&1);
  const f32x4 Z = {0.f,0.f,0.f,0.f};
  f32x4 acc[8];
  #pragma unroll
  for (int f8=0;f8<8;f8++) acc[f8] = Z;
  const bf16* xrow = xg + (size_t)(rt*16 + l15)*CC;
  #pragma unroll
  for (int t=0;t<4;t++){
    bf16x8 a = *(const bf16x8*)(xrow + t*32 + g*8);
    #pragma unroll
    for (int f8=0; f8<8; f8++){
      int h = f8>>1, fh = f8&1;
      bf16x8 bb = *(const bf16x8*)(qkvg + (((wm*4+h)*4+t)*2+fh)*512 + lane*8);
      acc[f8] = MFMA16(a, bb, acc[f8]);
    }
  }
  const int bq = rt/24, tau = rt%24;
  if (wm==1){
    char* scr = psm + w*4096;
    #pragma unroll
    for (int f8=0; f8<8; f8++){
      #pragma unroll
      for (int j=0;j<4;j++){
        unsigned r = g*4+j;
        *(bf16*)(scr + ((r*256 + (f8*16+l15)*2) ^ (((r>>1)&7)<<4))) = (bf16)acc[f8][j];
      }
    }
    #pragma unroll
    for (int h=0;h<4;h++){
      bf16x8 kf = *(const bf16x8*)(scr + ((l15*256 + h*64 + g*16) ^ (((l15>>1)&7)<<4)));
      *(bf16x8*)(kbuf + (((size_t)(bq*4+h)*24 + tau)*64 + lane)*8) = kf;
    }
  } else {
    int4 mi = *(const int4*)(mask + bq*NN + tau*16 + g*4);
    float mb[4] = { mi.x?1.f:0.f, mi.y?1.f:0.f, mi.z?1.f:0.f, mi.w?1.f:0.f };
    #pragma unroll
    for (int f8=0; f8<8; f8++){
      #pragma unroll
      for (int j=0;j<4;j++) acc[f8][j] *= mb[j];
    }
    #pragma unroll
    for (int h=0;h<4;h++){
      f32x4 a0 = acc[h*2+0], a1 = acc[h*2+1];
      uint4 st4;
      st4.x = bpack(a0[0], a0[1]);
      st4.y = bpack(a0[2], a0[3]);
      st4.z = bpack(a1[0], a1[1]);
      st4.w = bpack(a1[2], a1[3]);
      *(uint4*)((char*)vbuf + ((size_t)(bq*4+h)*24 + tau)*1024 + lane*16) = st4;
    }
  }
}

// ---------------- K3: attention v22 = v20 (measured session optimum) ----------------
// v21's V-from-L2 + paired tiles spilled (WRITE 101MB, VGPR at 128 arch cap) and
// occupancy stayed 2 waves/EU -> reverted. v20 config: paired q-tiles (2-way
// intra-wave ILP), K+V LDS-staged, fixed-max exp2 softmax with native
// v_exp/v_rcp, mask folded into zeroed-V + fmac denominator, nb as S-MFMA
// C-init, waves_per_eu(2,4) (the only no-spill budget).
#define L20_SCR  49152            // 4 waves x 2 KiB scratch (1 KiB per tile slot)
#define L20_MASK 57344            // fp32 0/1 [384]
#define L20_TOT  58880

__global__ __attribute__((amdgpu_flat_work_group_size(256,256), amdgpu_waves_per_eu(2,4)))
void attn_kernel20(
    const bf16* __restrict__ xg, const int* __restrict__ mask,
    const float* __restrict__ nb, const bf16* __restrict__ qkvg,
    bf16* __restrict__ kbuf, const bf16* __restrict__ vbuf,
    const float* __restrict__ gb)
{
  __shared__ char sm[L20_TOT];
  const int tid = threadIdx.x;
  const int lane = tid & 63, w = tid >> 6;
  const int g = (lane >> 4)&3, l15 = lane & 15;
  const f32x4 Z = {0.f,0.f,0.f,0.f};

  // h-major: concurrent blocks share one nb[h] plane (L2-resident)
  const u32 bid = blockIdx.x;
  const int h = bid / 384;
  const int b = bid - h*384;

  const char* kbh = (const char*)kbuf + ((size_t)b*4 + h)*24576;
  const char* vbh = (const char*)vbuf + ((size_t)b*4 + h)*24576;

  // ---- stage K (24KiB) + V (24KiB) + mask 0/1 fp32 (1.5KiB) ----
  #pragma unroll
  for (int i=0;i<6;i++){
    unsigned u = (i*4 + w)*1024;
    async_copy16(sm + u,         kbh + u + lane*16);
    async_copy16(sm + 24576 + u, vbh + u + lane*16);
  }
  for (int k = tid; k < NN; k += 256)
    *(float*)(sm + L20_MASK + k*4) = (mask[b*NN + k] != 0) ? 1.f : 0.f;
  __syncthreads();   // vmcnt+lgkm drain; all staging visible

  const unsigned scbA = L20_SCR + w*2048;
  const unsigned scbB = scbA + 1024;
  const float* nbh = nb + (size_t)h*(NN*NN);

  for (int i=0;i<3;i++){
    const int qtA = w*6 + i*2, qtB = qtA + 1;
    const int qbA = qtA*16,    qbB = qtB*16;

    // x A-frags for both q-tiles
    bf16x8 a4A[4], a4B[4];
    #pragma unroll
    for (int t=0;t<4;t++){
      a4A[t] = *(const bf16x8*)(xg + (size_t)(b*NN + qbA + l15)*CC + t*32 + g*8);
      a4B[t] = *(const bf16x8*)(xg + (size_t)(b*NN + qbB + l15)*CC + t*32 + g*8);
    }

    // ---- Q projections (weight frags shared) ----
    f32x4 qA0=Z, qA1=Z, qB0=Z, qB1=Z;
    #pragma unroll
    for (int t=0;t<4;t++){
      bf16x8 bq0 = *(const bf16x8*)(qkvg + (((0*4+h)*4+t)*2+0)*512 + lane*8);
      bf16x8 bq1 = *(const bf16x8*)(qkvg + (((0*4+h)*4+t)*2+1)*512 + lane*8);
      qA0 = MFMA16(a4A[t], bq0, qA0);
      qA1 = MFMA16(a4A[t], bq1, qA1);
      qB0 = MFMA16(a4B[t], bq0, qB0);
      qB1 = MFMA16(a4B[t], bq1, qB1);
    }
    // bounce both Q accums -> B-frags (separate slots; independent lgkm chains)
    #pragma unroll
    for (int f=0;f<2;f++){
      f32x4 qqA = f ? qA1 : qA0, qqB = f ? qB1 : qB0;
      #pragma unroll
      for (int j=0;j<4;j++){
        unsigned r = g*4 + j, cb = (f*16 + l15)*2;
        unsigned off = (r*64 + cb) ^ (((r>>1)&7)<<4);
        *(bf16*)(sm + scbA + off) = (bf16)qqA[j];
        *(bf16*)(sm + scbB + off) = (bf16)qqB[j];
      }
    }
    unsigned aqoff = (l15*64 + g*16) ^ (((l15>>1)&7)<<4);
    bf16x8 aqA = *(const bf16x8*)(sm + scbA + aqoff);
    bf16x8 aqB = *(const bf16x8*)(sm + scbB + aqoff);

    // ---- dual fixed-max softmax (no mask add) + register PV, six 64-key chunks ----
    float sumA = 0.f, sumB = 0.f;
    f32x4 oA0=Z, oA1=Z, oB0=Z, oB1=Z;
    const float* nbqA = nbh + (size_t)(qbA + l15)*NN;
    const float* nbqB = nbh + (size_t)(qbB + l15)*NN;

    #pragma unroll
    for (int c=0;c<6;c++){
      f32x4 stA[4], stB[4];
      #pragma unroll
      for (int nf=0;nf<4;nf++){
        bf16x8 ka = *(const bf16x8*)(sm + (c*4+nf)*1024 + lane*16);   // shared
        float4 nbvA = *(const float4*)(nbqA + c*64 + nf*16 + g*4);
        float4 nbvB = *(const float4*)(nbqB + c*64 + nf*16 + g*4);
        stA[nf] = MFMA16(ka, aqA, __builtin_bit_cast(f32x4, nbvA));
        stB[nf] = MFMA16(ka, aqB, __builtin_bit_cast(f32x4, nbvB));
      }
      #pragma unroll
      for (int nf=0;nf<4;nf++){
        float4 mkf = *(const float4*)(sm + L20_MASK + (c*64 + nf*16 + g*4)*4);  // shared 0/1
        const float* mk = &mkf.x;
        #pragma unroll
        for (int j=0;j<4;j++){
          float pvA = FEXP2(stA[nf][j] - 28.8539008178f);   // == exp(S - 20), no mask term
          float pvB = FEXP2(stB[nf][j] - 28.8539008178f);
          stA[nf][j] = pvA; sumA += pvA*mk[j];              // masked keys excluded via fmac
          stB[nf][j] = pvB; sumB += pvB*mk[j];
        }
      }
      #pragma unroll
      for (int nf=0;nf<4;nf++){
        bf16x8 vv = *(const bf16x8*)(sm + 24576 + (c*4+nf)*1024 + lane*16);   // shared (masked rows = 0)
        bf16x4v vlo = {vv[0],vv[1],vv[2],vv[3]};
        bf16x4v vhi = {vv[4],vv[5],vv[6],vv[7]};
        pvab_t paA = mk_pvab(bpack(stA[nf][0], stA[nf][1]), bpack(stA[nf][2], stA[nf][3]));
        pvab_t paB = mk_pvab(bpack(stB[nf][0], stB[nf][1]), bpack(stB[nf][2], stB[nf][3]));
        oA0 = PVMFMA(paA, vlo, oA0);
        oB0 = PVMFMA(paB, vlo, oB0);
        oA1 = PVMFMA(paA, vhi, oA1);
        oB1 = PVMFMA(paB, vhi, oB1);
      }
    } // c

    // deferred cross-lane sum reduces + broadcast to C/D rows
    sumA += __shfl_xor(sumA, 16); sumA += __shfl_xor(sumA, 32);
    sumB += __shfl_xor(sumB, 16); sumB += __shfl_xor(sumB, 32);
    float rslA = FRCP(sumA), rslB = FRCP(sumB);
    float rcdA[4], rcdB[4];
    #pragma unroll
    for (int j=0;j<4;j++){
      int src = (lane & 0x30) + g*4 + j;
      rcdA[j] = __shfl(rslA, src);
      rcdB[j] = __shfl(rslB, src);
    }

    // ---- gate projections (weight frags shared) ----
    f32x4 gA0=Z, gA1=Z, gB0=Z, gB1=Z;
    #pragma unroll
    for (int t=0;t<4;t++){
      bf16x8 bg0 = *(const bf16x8*)(qkvg + (((3*4+h)*4+t)*2+0)*512 + lane*8);
      bf16x8 bg1 = *(const bf16x8*)(qkvg + (((3*4+h)*4+t)*2+1)*512 + lane*8);
      gA0 = MFMA16(a4A[t], bg0, gA0);
      gA1 = MFMA16(a4A[t], bg1, gA1);
      gB0 = MFMA16(a4B[t], bg0, gB0);
      gB1 = MFMA16(a4B[t], bg1, gB1);
    }

    // ---- wg = (O/s)*sigmoid; bounce to A-frag per slot; store both wavg ----
    #pragma unroll
    for (int f=0;f<2;f++){
      f32x4 ovA = f ? oA1 : oA0, gvA = f ? gA1 : gA0;
      f32x4 ovB = f ? oB1 : oB0, gvB = f ? gB1 : gB0;
      int d = f*16 + l15;
      float gbv = gb[h*32 + d]*LOG2E;
      #pragma unroll
      for (int j=0;j<4;j++){
        unsigned r = g*4 + j, cb2 = (unsigned)d*2;
        unsigned off = (r*64 + cb2) ^ (((r>>1)&7)<<4);
        float gtA = FRCP(1.f + FEXP2(-(gvA[j] + gbv)));
        float gtB = FRCP(1.f + FEXP2(-(gvB[j] + gbv)));
        *(bf16*)(sm + scbA + off) = (bf16)(ovA[j]*rcdA[j]*gtA);
        *(bf16*)(sm + scbB + off) = (bf16)(ovB[j]*rcdB[j]*gtB);
      }
    }
    bf16x8 awgA = *(const bf16x8*)(sm + scbA + aqoff);
    bf16x8 awgB = *(const bf16x8*)(sm + scbB + aqoff);
    *(bf16x8*)((char*)kbuf + ((size_t)b*4 + h)*24576 + qtA*1024 + lane*16) = awgA;
    *(bf16x8*)((char*)kbuf + ((size_t)b*4 + h)*24576 + qtB*1024 + lane*16) = awgB;
  } // i (q-tile pairs)
}

// ---------------- K4: out-projection GEMM: out = wavg · o_w + ob ----------------
__global__ __launch_bounds__(256) void outproj_kernel(
    const bf16* __restrict__ wavg, const bf16* __restrict__ opk,
    const float* __restrict__ ob, float* __restrict__ out)
{
  const int w = threadIdx.x>>6, lane = threadIdx.x&63;
  const int g = (lane>>4)&3, l15 = lane&15;
  const f32x4 Z = {0.f,0.f,0.f,0.f};
  const int W = blockIdx.x*4 + w;
  const int b = W/24, qt = W%24, qb = qt*16;

  bf16x8 aw[4];
  #pragma unroll
  for (int h=0;h<4;h++)
    aw[h] = *(const bf16x8*)((const char*)wavg + ((size_t)b*4 + h)*24576 + qt*1024 + lane*16);

  f32x4 outa[8];
  #pragma unroll
  for (int nf=0;nf<8;nf++) outa[nf] = Z;
  #pragma unroll
  for (int h=0;h<4;h++){
    #pragma unroll
    for (int nf=0;nf<8;nf++){
      bf16x8 bo = *(const bf16x8*)(opk + ((h*8+nf)*64 + lane)*8);
      outa[nf] = MFMA16(aw[h], bo, outa[nf]);
    }
  }
  #pragma unroll
  for (int nf=0;nf<8;nf++){
    int c = nf*16 + l15;
    float obv = ob[c];
    #pragma unroll
    for (int j=0;j<4;j++){
      int qi = qb + g*4 + j;
      out[((size_t)b*NN + qi)*CC + c] = outa[nf][j] + obv;
    }
  }
}

extern "C" void kernel_launch(void* const* d_in, const int* in_sizes, int n_in,
                              void* d_out, int out_size, void* d_ws, size_t ws_size,
                              hipStream_t stream)
{
  (void)in_sizes; (void)n_in; (void)out_size; (void)ws_size;
  const float* pa  = (const float*)d_in[0];
  const int*   msk = (const int*)d_in[1];
  const float* lns = (const float*)d_in[2];
  const float* lnb = (const float*)d_in[3];
  const float* fw  = (const float*)d_in[4];
  const float* qw  = (const float*)d_in[5];
  const float* kw  = (const float*)d_in[6];
  const float* vw  = (const float*)d_in[7];
  const float* gw  = (const float*)d_in[8];
  const float* gbv = (const float*)d_in[9];
  const float* ow  = (const float*)d_in[10];
  const float* ob  = (const float*)d_in[11];
  float* out = (float*)d_out;

  char* ws = (char*)d_ws;
  bf16*  xbuf  = (bf16*)(ws);
  float* nbbuf = (float*)(ws + WS_NB);
  bf16*  qkvg  = (bf16*)(ws + WS_QKVG);
  bf16*  opk   = (bf16*)(ws + WS_OP);
  bf16*  kbuf  = (bf16*)(ws + WS_KB);
  bf16*  vbuf  = (bf16*)(ws + WS_VB);

  pack_kernel<<<40, 256, 0, stream>>>(qw, kw, vw, gw, ow, qkvg, opk);
  ln_kernel<<<1152, 256, 0, stream>>>(pa, lns, lnb, fw, xbuf, nbbuf);
  proj_kv_kernel<<<4608, 256, 0, stream>>>(xbuf, qkvg, msk, kbuf, vbuf);
  attn_kernel20<<<1536, 256, 0, stream>>>(xbuf, msk, nbbuf, qkvg, kbuf, vbuf, gbv);
  outproj_kernel<<<2304, 256, 0, stream>>>(kbuf, opk, ob, out);
}